// Round 1
// baseline (256.883 us; speedup 1.0000x reference)
//
#include <hip/hip_runtime.h>

// Problem constants (from reference): B=16, CIN=512, COUT=128, H=W=64
#define NB    16
#define CIN   512
#define COUT  128
#define HW    4096            // 64*64, contiguous innermost
#define BN    128             // N-tile per block
#define BK    32              // K-tile per iteration
#define NTILES (HW / BN)      // 32 n-tiles per batch

using bf16x8  = __attribute__((ext_vector_type(8))) __bf16;
using floatx4 = __attribute__((ext_vector_type(4))) float;

// RNE float -> bf16 bits
__device__ __forceinline__ unsigned short f2bf_bits(float f) {
    union { float f; unsigned u; } v; v.f = f;
    return (unsigned short)((v.u + 0x7fffu + ((v.u >> 16) & 1u)) >> 16);
}

__global__ __launch_bounds__(256, 2)
void modconv1x1_kernel(const float* __restrict__ x,
                       const float* __restrict__ style,
                       const float* __restrict__ weight,
                       float* __restrict__ out)
{
    // k-packed LDS layouts: element (k,m) at [k/8][m][k%8] -> frag read = 1 ds_read_b128
    __shared__ __align__(16) __bf16 Alds[(BK / 8) * COUT * 8];   // 8 KB
    __shared__ __align__(16) __bf16 Blds[(BK / 8) * BN * 8];     // 8 KB
    __shared__ float style_s[CIN];                               // 2 KB

    const int tid  = threadIdx.x;
    const int bidx = blockIdx.x;
    const int b    = bidx >> 5;          // batch
    const int n0   = (bidx & 31) * BN;   // hw tile start

    const float* xb   = x   + (size_t)b * CIN * HW + n0;
    float*       outb = out + (size_t)b * COUT * HW + n0;

    // stage style row (512 floats) once
    style_s[tid]       = style[b * CIN + tid];
    style_s[tid + 256] = style[b * CIN + tid + 256];

    floatx4 acc[4][4];
    #pragma unroll
    for (int i = 0; i < 4; ++i)
        #pragma unroll
        for (int j = 0; j < 4; ++j)
            acc[i][j] = (floatx4){0.f, 0.f, 0.f, 0.f};

    const int lane = tid & 63;
    const int wave = tid >> 6;
    const int quad = lane >> 4;
    const int l15  = lane & 15;
    const int wm   = (wave & 1) * 64;    // wave's M offset
    const int wn   = (wave >> 1) * 64;   // wave's N offset

    // A staging: pair p = tid + 256*i -> m = p>>2 (+64*i), k8 = tid&3
    const int am  = tid >> 2;
    const int ak8 = tid & 3;
    // B staging: pair p = tid + 256*i -> n = tid&127, k8 = (tid>>7) + 2*i
    const int bn_ = tid & 127;
    const int bk8 = tid >> 7;

    __syncthreads();   // style_s ready

    for (int k0 = 0; k0 < CIN; k0 += BK) {
        // ---- stage A tile: bf16(weight[m][k] * style[k]), layout [k8][m][j] ----
        #pragma unroll
        for (int i = 0; i < 2; ++i) {
            const int m  = am + i * 64;
            const int kb = k0 + ak8 * 8;
            const float4 w0 = *(const float4*)(weight + m * CIN + kb);
            const float4 w1 = *(const float4*)(weight + m * CIN + kb + 4);
            union { unsigned short us[8]; bf16x8 v; } pk;
            pk.us[0] = f2bf_bits(w0.x * style_s[kb + 0]);
            pk.us[1] = f2bf_bits(w0.y * style_s[kb + 1]);
            pk.us[2] = f2bf_bits(w0.z * style_s[kb + 2]);
            pk.us[3] = f2bf_bits(w0.w * style_s[kb + 3]);
            pk.us[4] = f2bf_bits(w1.x * style_s[kb + 4]);
            pk.us[5] = f2bf_bits(w1.y * style_s[kb + 5]);
            pk.us[6] = f2bf_bits(w1.z * style_s[kb + 6]);
            pk.us[7] = f2bf_bits(w1.w * style_s[kb + 7]);
            *(bf16x8*)&Alds[(ak8 * COUT + m) * 8] = pk.v;
        }
        // ---- stage B tile: bf16(x[k][n]) transposed to [k8][n][j] ----
        #pragma unroll
        for (int i = 0; i < 2; ++i) {
            const int k8 = bk8 + i * 2;
            const float* src = xb + (size_t)(k0 + k8 * 8) * HW + bn_;
            union { unsigned short us[8]; bf16x8 v; } pk;
            #pragma unroll
            for (int j = 0; j < 8; ++j)
                pk.us[j] = f2bf_bits(src[j * HW]);   // 256B wave-coalesced per j
            *(bf16x8*)&Blds[(k8 * BN + bn_) * 8] = pk.v;
        }
        __syncthreads();

        // ---- compute: 4x4 tiles of 16x16x32 per wave ----
        bf16x8 af[4], bfr[4];
        #pragma unroll
        for (int tm = 0; tm < 4; ++tm)
            af[tm] = *(const bf16x8*)&Alds[(quad * COUT + wm + tm * 16 + l15) * 8];
        #pragma unroll
        for (int tn = 0; tn < 4; ++tn)
            bfr[tn] = *(const bf16x8*)&Blds[(quad * BN + wn + tn * 16 + l15) * 8];
        #pragma unroll
        for (int tm = 0; tm < 4; ++tm)
            #pragma unroll
            for (int tn = 0; tn < 4; ++tn)
                acc[tm][tn] = __builtin_amdgcn_mfma_f32_16x16x32_bf16(
                    af[tm], bfr[tn], acc[tm][tn], 0, 0, 0);
        __syncthreads();
    }

    // ---- epilogue: C/D layout col=lane&15 (n), row=quad*4+reg (o) ----
    #pragma unroll
    for (int tm = 0; tm < 4; ++tm) {
        const int o = wm + tm * 16 + quad * 4;
        #pragma unroll
        for (int tn = 0; tn < 4; ++tn) {
            const int n = wn + tn * 16 + l15;
            #pragma unroll
            for (int r = 0; r < 4; ++r)
                outb[(size_t)(o + r) * HW + n] = acc[tm][tn][r];
        }
    }
}

extern "C" void kernel_launch(void* const* d_in, const int* in_sizes, int n_in,
                              void* d_out, int out_size, void* d_ws, size_t ws_size,
                              hipStream_t stream) {
    const float* x      = (const float*)d_in[0];   // (16, 512, 64, 64) fp32
    const float* style  = (const float*)d_in[1];   // (16, 512) fp32
    const float* weight = (const float*)d_in[2];   // (128, 512) fp32
    float* out = (float*)d_out;                    // (16, 128, 64, 64) fp32

    modconv1x1_kernel<<<dim3(NB * NTILES), dim3(256), 0, stream>>>(x, style, weight, out);
}

// Round 2
// 218.938 us; speedup vs baseline: 1.1733x; 1.1733x over previous
//
#include <hip/hip_runtime.h>

// B=16, CIN=512, COUT=128, H=W=64
#define NB    16
#define CIN   512
#define COUT  128
#define HW    4096
#define BN    64              // N-tile per block
#define BK    32              // K-tile per iteration
#define NIT   (CIN / BK)      // 16
#define NTILES (HW / BN)      // 64 -> grid = 1024 blocks = 4 blocks/CU

using bf16x8  = __attribute__((ext_vector_type(8))) __bf16;
using floatx4 = __attribute__((ext_vector_type(4))) float;

// RNE float -> bf16 bits
__device__ __forceinline__ unsigned short f2bf_bits(float f) {
    union { float f; unsigned u; } v; v.f = f;
    return (unsigned short)((v.u + 0x7fffu + ((v.u >> 16) & 1u)) >> 16);
}

__global__ __launch_bounds__(256, 4)
void modconv1x1_kernel(const float* __restrict__ x,
                       const float* __restrict__ style,
                       const float* __restrict__ weight,
                       float* __restrict__ out)
{
    // A: [buf][k8-slab(128 units) ; unit = m ^ (2*k8)][8 bf16]  -- XOR swizzle kills
    //    the 4-way ds_write_b128 bank conflict while keeping reads consecutive-set.
    __shared__ __align__(16) __bf16 Alds[2][(BK / 8) * COUT * 8];  // 2 x 8 KB
    __shared__ __align__(16) __bf16 Blds[2][(BK / 8) * BN * 8];    // 2 x 4 KB
    __shared__ float style_s[CIN];                                 // 2 KB

    const int tid = threadIdx.x;
    const int b   = blockIdx.x >> 6;           // batch
    const int n0  = (blockIdx.x & 63) * BN;    // hw tile start

    const float* xb   = x   + (size_t)b * CIN * HW + n0;
    float*       outb = out + (size_t)b * COUT * HW + n0;

    style_s[tid]       = style[b * CIN + tid];
    style_s[tid + 256] = style[b * CIN + tid + 256];

    const int lane = tid & 63;
    const int wave = tid >> 6;
    const int quad = lane >> 4;
    const int l15  = lane & 15;
    const int wm   = (wave & 1) * 64;    // wave M offset (wave tile 64x32)
    const int wn   = (wave >> 1) * 32;   // wave N offset

    // A staging: thread -> (m = (tid>>2) + 64*i, k8 = tid&3), i in {0,1}
    const int am  = tid >> 2;
    const int ak8 = tid & 3;
    // B staging: thread -> (n = lane, k8 = wave), 8 consecutive k
    const int bn_ = lane;
    const int bk8 = wave;

    floatx4 acc[4][2];
    #pragma unroll
    for (int i = 0; i < 4; ++i)
        #pragma unroll
        for (int j = 0; j < 2; ++j)
            acc[i][j] = (floatx4){0.f, 0.f, 0.f, 0.f};

    // Prefetch registers: all global loads of a tile issued together (MLP).
    float4 ra[2][2];
    float  rb[8];

#define LOAD_TILE(K0)                                                          \
    {                                                                          \
        const int kb = (K0) + ak8 * 8;                                         \
        _Pragma("unroll")                                                      \
        for (int i = 0; i < 2; ++i) {                                          \
            ra[i][0] = *(const float4*)(weight + (am + 64 * i) * CIN + kb);    \
            ra[i][1] = *(const float4*)(weight + (am + 64 * i) * CIN + kb + 4);\
        }                                                                      \
        const float* src = xb + (size_t)((K0) + bk8 * 8) * HW + bn_;           \
        _Pragma("unroll")                                                      \
        for (int j = 0; j < 8; ++j)                                            \
            rb[j] = src[(size_t)j * HW];                                       \
    }

#define WRITE_TILE(BUF, K0)                                                    \
    {                                                                          \
        const int kb = (K0) + ak8 * 8;                                         \
        _Pragma("unroll")                                                      \
        for (int i = 0; i < 2; ++i) {                                          \
            const float* rap = (const float*)&ra[i][0];                        \
            union { unsigned short us[8]; bf16x8 v; } pk;                      \
            _Pragma("unroll")                                                  \
            for (int j = 0; j < 8; ++j)                                        \
                pk.us[j] = f2bf_bits(rap[j] * style_s[kb + j]);                \
            const int unit = 128 * ak8 + ((am + 64 * i) ^ (ak8 << 1));         \
            *(bf16x8*)&Alds[BUF][unit * 8] = pk.v;                             \
        }                                                                      \
        union { unsigned short us[8]; bf16x8 v; } pb;                          \
        _Pragma("unroll")                                                      \
        for (int j = 0; j < 8; ++j)                                            \
            pb.us[j] = f2bf_bits(rb[j]);                                       \
        *(bf16x8*)&Blds[BUF][(64 * bk8 + bn_) * 8] = pb.v;                     \
    }

    __syncthreads();   // style_s ready

    // Prologue: tile 0 into buf 0
    LOAD_TILE(0)
    WRITE_TILE(0, 0)

    int cur = 0;
    for (int it = 0; it < NIT; ++it) {
        const int knext = (it + 1) * BK;
        __syncthreads();                 // buf[cur] visible to all waves
        if (it + 1 < NIT) LOAD_TILE(knext)   // issue next tile's loads ASAP

        bf16x8 af[4], bfr[2];
        #pragma unroll
        for (int tm = 0; tm < 4; ++tm) {
            const int unit = 128 * quad + ((wm + tm * 16 + l15) ^ (quad << 1));
            af[tm] = *(const bf16x8*)&Alds[cur][unit * 8];
        }
        #pragma unroll
        for (int tn = 0; tn < 2; ++tn)
            bfr[tn] = *(const bf16x8*)&Blds[cur][(64 * quad + wn + tn * 16 + l15) * 8];
        #pragma unroll
        for (int tm = 0; tm < 4; ++tm)
            #pragma unroll
            for (int tn = 0; tn < 2; ++tn)
                acc[tm][tn] = __builtin_amdgcn_mfma_f32_16x16x32_bf16(
                    af[tm], bfr[tn], acc[tm][tn], 0, 0, 0);

        if (it + 1 < NIT) WRITE_TILE(cur ^ 1, knext)
        cur ^= 1;
    }

    // Epilogue: C/D layout col(n)=lane&15, row(o)=quad*4+reg
    #pragma unroll
    for (int tm = 0; tm < 4; ++tm) {
        const int o = wm + tm * 16 + quad * 4;
        #pragma unroll
        for (int tn = 0; tn < 2; ++tn) {
            const int n = wn + tn * 16 + l15;
            #pragma unroll
            for (int r = 0; r < 4; ++r)
                outb[(size_t)(o + r) * HW + n] = acc[tm][tn][r];
        }
    }
#undef LOAD_TILE
#undef WRITE_TILE
}

extern "C" void kernel_launch(void* const* d_in, const int* in_sizes, int n_in,
                              void* d_out, int out_size, void* d_ws, size_t ws_size,
                              hipStream_t stream) {
    const float* x      = (const float*)d_in[0];   // (16, 512, 64, 64) fp32
    const float* style  = (const float*)d_in[1];   // (16, 512) fp32
    const float* weight = (const float*)d_in[2];   // (128, 512) fp32
    float* out = (float*)d_out;                    // (16, 128, 64, 64) fp32

    modconv1x1_kernel<<<dim3(NB * NTILES), dim3(256), 0, stream>>>(x, style, weight, out);
}

// Round 3
// 212.975 us; speedup vs baseline: 1.2062x; 1.0280x over previous
//
#include <hip/hip_runtime.h>
#include <stdint.h>

// B=16, CIN=512, COUT=128, H=W=64
#define NB    16
#define CIN   512
#define COUT  128
#define HW    4096
#define BN    64              // N-tile per block
#define BK    32              // K-tile per iteration
#define NIT   (CIN / BK)      // 16
#define NTILES (HW / BN)      // 64 -> grid = 1024 blocks = 4 blocks/CU

using bf16x8  = __attribute__((ext_vector_type(8))) __bf16;
using floatx4 = __attribute__((ext_vector_type(4))) float;

// RNE float -> bf16 bits (proven correct in R1/R2)
__device__ __forceinline__ unsigned short f2bf_bits(float f) {
    union { float f; unsigned u; } v; v.f = f;
    return (unsigned short)((v.u + 0x7fffu + ((v.u >> 16) & 1u)) >> 16);
}

// async global->LDS, 16B per lane, LDS dest = wave-uniform base + lane*16
#define GLD16(g, l)                                                            \
    __builtin_amdgcn_global_load_lds(                                          \
        (const __attribute__((address_space(1))) void*)(g),                    \
        (__attribute__((address_space(3))) void*)(l), 16, 0, 0)

// ---------------------------------------------------------------------------
// Precompute mw[b][k8][m][j] = bf16(weight[m][k8*8+j] * style[b][k8*8+j])
// Layout matches the main kernel's LDS A-tile exactly: tile k0 is the 8KB
// contiguous slab at byte offset k0*256 within batch b's 128KB region.
// ---------------------------------------------------------------------------
__global__ __launch_bounds__(256)
void modw_kernel(const float* __restrict__ style,
                 const float* __restrict__ weight,
                 __bf16* __restrict__ mw)
{
    const int id = blockIdx.x * 256 + threadIdx.x;   // 512 blocks * 256 = 131072
    const int k8 = id & 63;
    const int m  = (id >> 6) & 127;
    const int b  = id >> 13;

    const float4 w0 = *(const float4*)(weight + m * CIN + k8 * 8);
    const float4 w1 = *(const float4*)(weight + m * CIN + k8 * 8 + 4);
    const float4 s0 = *(const float4*)(style + b * CIN + k8 * 8);
    const float4 s1 = *(const float4*)(style + b * CIN + k8 * 8 + 4);

    union { unsigned short us[8]; bf16x8 v; } pk;
    pk.us[0] = f2bf_bits(w0.x * s0.x);
    pk.us[1] = f2bf_bits(w0.y * s0.y);
    pk.us[2] = f2bf_bits(w0.z * s0.z);
    pk.us[3] = f2bf_bits(w0.w * s0.w);
    pk.us[4] = f2bf_bits(w1.x * s1.x);
    pk.us[5] = f2bf_bits(w1.y * s1.y);
    pk.us[6] = f2bf_bits(w1.z * s1.z);
    pk.us[7] = f2bf_bits(w1.w * s1.w);
    *(bf16x8*)(mw + ((size_t)(b * 64 + k8) * 128 + m) * 8) = pk.v;
}

// ---------------------------------------------------------------------------
// Main GEMM: out[b,o,n] = sum_c mw[b,o,c] * x[b,c,n], per-block 128x64 tile.
// A-staging: 2x global_load_lds_dwordx4 per wave (no regs, no VALU).
// B-staging: 8 coalesced strided dwords -> bf16 -> 1x ds_write_b128.
// ---------------------------------------------------------------------------
__global__ __launch_bounds__(256, 4)
void modconv1x1_kernel(const float* __restrict__ x,
                       const __bf16* __restrict__ mw,
                       float* __restrict__ out)
{
    __shared__ __align__(16) __bf16 Alds[2][(BK / 8) * COUT * 8];  // 2 x 8 KB
    __shared__ __align__(16) __bf16 Blds[2][(BK / 8) * BN * 8];    // 2 x 4 KB

    const int tid = threadIdx.x;
    const int b   = blockIdx.x >> 6;
    const int n0  = (blockIdx.x & 63) * BN;

    const float* xb   = x   + (size_t)b * CIN * HW + n0;
    float*       outb = out + (size_t)b * COUT * HW + n0;
    const char*  mwb  = (const char*)mw + (size_t)b * (64 * 128 * 16);  // 128KB/batch

    const int lane = tid & 63;
    const int wave = tid >> 6;
    const int quad = lane >> 4;
    const int l15  = lane & 15;
    const int wm   = (wave & 1) * 64;    // wave M offset (64x32 wave tile)
    const int wn   = (wave >> 1) * 32;   // wave N offset

    const int bn_ = lane;                // B staging: n = lane
    const int bk8 = wave;                // B staging: k8-slab = wave

    floatx4 acc[4][2];
    #pragma unroll
    for (int i = 0; i < 4; ++i)
        #pragma unroll
        for (int j = 0; j < 2; ++j)
            acc[i][j] = (floatx4){0.f, 0.f, 0.f, 0.f};

    // ---- prologue: tile 0 into buf 0 ----
    {
        const char* t  = mwb;                       // k0 = 0
        char*       al = (char*)&Alds[0][0];
        GLD16(t + wave * 2048 + lane * 16,        al + wave * 2048);
        GLD16(t + wave * 2048 + 1024 + lane * 16, al + wave * 2048 + 1024);

        const float* src = xb + (size_t)(bk8 * 8) * HW + bn_;
        float rb[8];
        #pragma unroll
        for (int j = 0; j < 8; ++j) rb[j] = src[(size_t)j * HW];
        union { unsigned short us[8]; bf16x8 v; } pk;
        #pragma unroll
        for (int j = 0; j < 8; ++j) pk.us[j] = f2bf_bits(rb[j]);
        *(bf16x8*)&Blds[0][(bk8 * BN + bn_) * 8] = pk.v;
    }

    int cur = 0;
    for (int it = 0; it < NIT; ++it) {
        __syncthreads();   // buf[cur] complete (compiler drains vmcnt before barrier)

        float rb[8];
        if (it + 1 < NIT) {
            const int knext = (it + 1) * BK;
            // A(next) straight to LDS
            const char* t  = mwb + (size_t)knext * 256;
            char*       al = (char*)&Alds[cur ^ 1][0];
            GLD16(t + wave * 2048 + lane * 16,        al + wave * 2048);
            GLD16(t + wave * 2048 + 1024 + lane * 16, al + wave * 2048 + 1024);
            // B(next) into regs (8 fully-coalesced 256B wave transactions)
            const float* src = xb + (size_t)(knext + bk8 * 8) * HW + bn_;
            #pragma unroll
            for (int j = 0; j < 8; ++j) rb[j] = src[(size_t)j * HW];
        }

        // ---- compute on buf[cur]: 4x2 tiles of 16x16x32 per wave ----
        bf16x8 af[4], bfr[2];
        #pragma unroll
        for (int tm = 0; tm < 4; ++tm)
            af[tm] = *(const bf16x8*)&Alds[cur][(quad * COUT + wm + tm * 16 + l15) * 8];
        #pragma unroll
        for (int tn = 0; tn < 2; ++tn)
            bfr[tn] = *(const bf16x8*)&Blds[cur][(quad * BN + wn + tn * 16 + l15) * 8];
        #pragma unroll
        for (int tm = 0; tm < 4; ++tm)
            #pragma unroll
            for (int tn = 0; tn < 2; ++tn)
                acc[tm][tn] = __builtin_amdgcn_mfma_f32_16x16x32_bf16(
                    af[tm], bfr[tn], acc[tm][tn], 0, 0, 0);

        if (it + 1 < NIT) {
            union { unsigned short us[8]; bf16x8 v; } pk;
            #pragma unroll
            for (int j = 0; j < 8; ++j) pk.us[j] = f2bf_bits(rb[j]);
            *(bf16x8*)&Blds[cur ^ 1][(bk8 * BN + bn_) * 8] = pk.v;
        }
        cur ^= 1;
    }

    // ---- epilogue: C/D layout col(n)=lane&15, row(o)=quad*4+reg ----
    #pragma unroll
    for (int tm = 0; tm < 4; ++tm) {
        const int o = wm + tm * 16 + quad * 4;
        #pragma unroll
        for (int tn = 0; tn < 2; ++tn) {
            const int n = wn + tn * 16 + l15;
            #pragma unroll
            for (int r = 0; r < 4; ++r)
                outb[(size_t)(o + r) * HW + n] = acc[tm][tn][r];
        }
    }
}

extern "C" void kernel_launch(void* const* d_in, const int* in_sizes, int n_in,
                              void* d_out, int out_size, void* d_ws, size_t ws_size,
                              hipStream_t stream) {
    const float* x      = (const float*)d_in[0];   // (16, 512, 64, 64) fp32
    const float* style  = (const float*)d_in[1];   // (16, 512) fp32
    const float* weight = (const float*)d_in[2];   // (128, 512) fp32
    float* out = (float*)d_out;                    // (16, 128, 64, 64) fp32
    __bf16* mw = (__bf16*)d_ws;                    // 2 MB modulated weights

    modw_kernel<<<dim3(512), dim3(256), 0, stream>>>(style, weight, mw);
    modconv1x1_kernel<<<dim3(NB * NTILES), dim3(256), 0, stream>>>(x, mw, out);
}